// Round 11
// baseline (1134.229 us; speedup 1.0000x reference)
//
#include <hip/hip_runtime.h>
#include <hip/hip_bf16.h>

typedef _Float16 f16;
typedef _Float16 f16x8 __attribute__((ext_vector_type(8)));
typedef _Float16 f16x4v __attribute__((ext_vector_type(4)));
typedef _Float16 h2 __attribute__((ext_vector_type(2)));
typedef float f32x4 __attribute__((ext_vector_type(4)));
typedef unsigned ui4v __attribute__((ext_vector_type(4)));
typedef unsigned short u16x4 __attribute__((ext_vector_type(4)));
typedef unsigned long long ull;

#define B_ 8
#define S_ 512
#define H_ 768
#define V_ 35004
#define J_ 30
#define K_ 9
#define R_ 2160          // B*J*K rows, row r = b*270 + j*9 + t  (matches out layout)
#define H3 2304
#define VMT 17           // vocab M tiles
#define VNT 274          // vocab N tiles

// ---------------------------------------------------------------- prep kernels

__global__ void k_zero(int* p, int n) {
    int i = blockIdx.x * 256 + threadIdx.x;
    if (i < n) p[i] = 0;
}

__global__ void k_cast(const float* __restrict__ s, f16* __restrict__ d, long n) {
    for (long i = (long)blockIdx.x * 256 + threadIdx.x; i < n; i += (long)gridDim.x * 256)
        d[i] = (f16)s[i];
}

// W_all[r] = (t==0) ? decoder_input[b,j,:] : embed[teacher[b,j,t-1],:]
__global__ void k_build_wall(const float* __restrict__ emb, const float* __restrict__ dec,
                             const int* __restrict__ teacher, f16* __restrict__ Wall) {
    int r = blockIdx.x;
    int b = r / 270, s = r % 270, j = s / 9, t = s % 9;
    const float* src = (t == 0) ? dec + ((long)b * J_ + j) * H_
                                : emb + (long)teacher[((long)b * J_ + j) * K_ + (t - 1)] * H_;
    f16* dst = Wall + (long)r * H_;
    for (int c = threadIdx.x; c < H_; c += 256) dst[c] = (f16)src[c];
}

// h exchange word: {seq:32 | f32 bits:32}; chain-major [chain][parity][768]
__global__ void k_init_h(const float* __restrict__ hidden, ull* __restrict__ hbuf) {
    int i = blockIdx.x * 256 + threadIdx.x;
    if (i < B_ * H_) {
        int b = i / H_, u = i % H_;
        hbuf[(long)b * 1536 + u] = (ull)__float_as_uint(hidden[i]);  // seq 0, parity 0
    }
}

// ---------------------------------------------------------------- shared GEMM helpers
typedef const __attribute__((address_space(1))) unsigned GASU;
typedef __attribute__((address_space(3))) unsigned LASU;
__device__ __forceinline__ void gld16(const f16* g, f16* l) {
    __builtin_amdgcn_global_load_lds((GASU*)g, (LASU*)l, 16, 0, 0);
}

// ---------------------------------------------------------------- f16 MFMA GEMM (m97 structure)
// C[M,N] = A[M,K] @ B[N,K]^T ; MODE 0: store, 1: store + bias[col]
template <int MODE>
__global__ __launch_bounds__(256) void k_gemm(const f16* __restrict__ A, const f16* __restrict__ Bm,
                                              float* __restrict__ C, const float* __restrict__ bias,
                                              int M, int N, int K, long sA, long sB, long sC) {
    A += (long)blockIdx.z * sA;
    Bm += (long)blockIdx.z * sB;
    C += (long)blockIdx.z * sC;
    const int m0 = blockIdx.y * 128, n0 = blockIdx.x * 128;
    __shared__ f16 As[128 * 32];
    __shared__ f16 Bs[128 * 32];
    const int tid = threadIdx.x, lane = tid & 63, wave = tid >> 6;
    const int wm = wave >> 1, wn = wave & 1;
    const int fr = lane & 15, kg = lane >> 4;
    f32x4 acc[4][4] = {};
    const int idxu = wave * 128;
    const int i0 = idxu + lane, i1 = idxu + 64 + lane;
    const int r0 = i0 >> 2, k80 = i0 & 3;
    const int r1 = i1 >> 2, k81 = i1 & 3;
    int ga0 = m0 + r0; if (ga0 >= M) ga0 = M - 1;
    int ga1 = m0 + r1; if (ga1 >= M) ga1 = M - 1;
    int gb0 = n0 + r0; if (gb0 >= N) gb0 = N - 1;
    int gb1 = n0 + r1; if (gb1 >= N) gb1 = N - 1;
    const f16* pa0 = A + (long)ga0 * K + k80 * 8;
    const f16* pa1 = A + (long)ga1 * K + k81 * 8;
    const f16* pb0 = Bm + (long)gb0 * K + k80 * 8;
    const f16* pb1 = Bm + (long)gb1 * K + k81 * 8;
    for (int kt = 0; kt < K; kt += 32) {
        gld16(pa0 + kt, As + idxu * 8);
        gld16(pa1 + kt, As + idxu * 8 + 512);
        gld16(pb0 + kt, Bs + idxu * 8);
        gld16(pb1 + kt, Bs + idxu * 8 + 512);
        __syncthreads();
        f16x8 af[4], bf[4];
#pragma unroll
        for (int m = 0; m < 4; ++m) af[m] = *(const f16x8*)(As + (wm * 64 + m * 16 + fr) * 32 + kg * 8);
#pragma unroll
        for (int n = 0; n < 4; ++n) bf[n] = *(const f16x8*)(Bs + (wn * 64 + n * 16 + fr) * 32 + kg * 8);
#pragma unroll
        for (int m = 0; m < 4; ++m)
#pragma unroll
            for (int n = 0; n < 4; ++n)
                acc[m][n] = __builtin_amdgcn_mfma_f32_16x16x32_f16(af[m], bf[n], acc[m][n], 0, 0, 0);
        __syncthreads();
    }
    const int crow = m0 + wm * 64 + (lane >> 4) * 4;
    const int ccol = n0 + wn * 64 + fr;
#pragma unroll
    for (int n = 0; n < 4; ++n) {
        int col = ccol + n * 16;
        if (col >= N) continue;
        float bv = (MODE == 1) ? bias[col] : 0.f;
#pragma unroll
        for (int m = 0; m < 4; ++m) {
#pragma unroll
            for (int q = 0; q < 4; ++q) {
                int row = crow + m * 16 + q;
                if (row < M) C[(long)row * N + col] = acc[m][n][q] + bv;
            }
        }
    }
}

// ---------------------------------------------------------------- merged hi/lo attention logits
__global__ __launch_bounds__(256) void k_attn3(const f16* __restrict__ Ahi, const f16* __restrict__ Alo,
                                               const f16* __restrict__ Bhi, const f16* __restrict__ Blo,
                                               float* __restrict__ C, int M, int N, int K,
                                               long sA, long sB, long sC) {
    const long za = (long)blockIdx.z * sA, zb = (long)blockIdx.z * sB;
    C += (long)blockIdx.z * sC;
    const int m0 = blockIdx.y * 128, n0 = blockIdx.x * 128;
    __shared__ f16 As[128 * 32];
    __shared__ f16 Bs[128 * 32];
    const int tid = threadIdx.x, lane = tid & 63, wave = tid >> 6;
    const int wm = wave >> 1, wn = wave & 1;
    const int fr = lane & 15, kg = lane >> 4;
    f32x4 acc[4][4] = {};
    const int idxu = wave * 128;
    const int i0 = idxu + lane, i1 = idxu + 64 + lane;
    const int r0 = i0 >> 2, k80 = i0 & 3;
    const int r1 = i1 >> 2, k81 = i1 & 3;
    int ga0 = m0 + r0; if (ga0 >= M) ga0 = M - 1;
    int ga1 = m0 + r1; if (ga1 >= M) ga1 = M - 1;
    int gb0 = n0 + r0; if (gb0 >= N) gb0 = N - 1;
    int gb1 = n0 + r1; if (gb1 >= N) gb1 = N - 1;
    const long oa0 = (long)ga0 * K + k80 * 8, oa1 = (long)ga1 * K + k81 * 8;
    const long ob0 = (long)gb0 * K + k80 * 8, ob1 = (long)gb1 * K + k81 * 8;
    for (int ph = 0; ph < 3; ++ph) {
        const f16* Ap = (ph == 2 ? Alo : Ahi) + za;
        const f16* Bp = (ph == 1 ? Blo : Bhi) + zb;
        for (int kt = 0; kt < K; kt += 32) {
            gld16(Ap + oa0 + kt, As + idxu * 8);
            gld16(Ap + oa1 + kt, As + idxu * 8 + 512);
            gld16(Bp + ob0 + kt, Bs + idxu * 8);
            gld16(Bp + ob1 + kt, Bs + idxu * 8 + 512);
            __syncthreads();
            f16x8 af[4], bf[4];
#pragma unroll
            for (int m = 0; m < 4; ++m) af[m] = *(const f16x8*)(As + (wm * 64 + m * 16 + fr) * 32 + kg * 8);
#pragma unroll
            for (int n = 0; n < 4; ++n) bf[n] = *(const f16x8*)(Bs + (wn * 64 + n * 16 + fr) * 32 + kg * 8);
#pragma unroll
            for (int m = 0; m < 4; ++m)
#pragma unroll
                for (int n = 0; n < 4; ++n)
                    acc[m][n] = __builtin_amdgcn_mfma_f32_16x16x32_f16(af[m], bf[n], acc[m][n], 0, 0, 0);
            __syncthreads();
        }
    }
    const int crow = m0 + wm * 64 + (lane >> 4) * 4;
    const int ccol = n0 + wn * 64 + fr;
#pragma unroll
    for (int n = 0; n < 4; ++n) {
        int col = ccol + n * 16;
        if (col >= N) continue;
#pragma unroll
        for (int m = 0; m < 4; ++m) {
#pragma unroll
            for (int q = 0; q < 4; ++q) {
                int row = crow + m * 16 + q;
                if (row < M) C[(long)row * N + col] = acc[m][n][q];
            }
        }
    }
}

// ---------------------------------------------------------------- vocab GEMM
// BF16OUT=0: Cf = exp(A@B^T) f32. BF16OUT=1: Ch = bf16(exp(A@B^T)).
// Both emit per-block per-row partial sums (f32, pre-rounding) -> psum[nt][row].
template <int BF16OUT>
__global__ __launch_bounds__(256) void k_vocab(const f16* __restrict__ A, const f16* __restrict__ Bm,
                                               float* __restrict__ Cf, unsigned short* __restrict__ Ch,
                                               float* __restrict__ psum) {
    const int M = R_, N = V_, K = H_;
    const int nwg = VMT * VNT;
    int lin = blockIdx.x;
    int q8 = nwg / 8, r8 = nwg % 8;
    int xcd = lin & 7, idx = lin >> 3;
    int newlin = (xcd < r8) ? xcd * (q8 + 1) + idx : r8 * (q8 + 1) + (xcd - r8) * q8 + idx;
    int mt = newlin % VMT, nt = newlin / VMT;
    const int m0 = mt * 128, n0 = nt * 128;
    __shared__ f16 As[128 * 32];
    __shared__ f16 Bs[128 * 32];
    __shared__ float rpart[2][128];
    const int tid = threadIdx.x, lane = tid & 63, wave = tid >> 6;
    const int wm = wave >> 1, wn = wave & 1;
    const int fr = lane & 15, kg = lane >> 4;
    f32x4 acc[4][4] = {};
    const int idxu = wave * 128;
    const int i0 = idxu + lane, i1 = idxu + 64 + lane;
    const int r0 = i0 >> 2, k80 = i0 & 3;
    const int r1 = i1 >> 2, k81 = i1 & 3;
    int ga0 = m0 + r0; if (ga0 >= M) ga0 = M - 1;
    int ga1 = m0 + r1; if (ga1 >= M) ga1 = M - 1;
    int gb0 = n0 + r0; if (gb0 >= N) gb0 = N - 1;
    int gb1 = n0 + r1; if (gb1 >= N) gb1 = N - 1;
    const f16* pa0 = A + (long)ga0 * K + k80 * 8;
    const f16* pa1 = A + (long)ga1 * K + k81 * 8;
    const f16* pb0 = Bm + (long)gb0 * K + k80 * 8;
    const f16* pb1 = Bm + (long)gb1 * K + k81 * 8;
    for (int kt = 0; kt < K; kt += 32) {
        gld16(pa0 + kt, As + idxu * 8);
        gld16(pa1 + kt, As + idxu * 8 + 512);
        gld16(pb0 + kt, Bs + idxu * 8);
        gld16(pb1 + kt, Bs + idxu * 8 + 512);
        __syncthreads();
        f16x8 af[4], bf[4];
#pragma unroll
        for (int m = 0; m < 4; ++m) af[m] = *(const f16x8*)(As + (wm * 64 + m * 16 + fr) * 32 + kg * 8);
#pragma unroll
        for (int n = 0; n < 4; ++n) bf[n] = *(const f16x8*)(Bs + (wn * 64 + n * 16 + fr) * 32 + kg * 8);
#pragma unroll
        for (int m = 0; m < 4; ++m)
#pragma unroll
            for (int n = 0; n < 4; ++n)
                acc[m][n] = __builtin_amdgcn_mfma_f32_16x16x32_f16(af[m], bf[n], acc[m][n], 0, 0, 0);
        __syncthreads();
    }
    const int crow = m0 + wm * 64 + (lane >> 4) * 4;
    const int ccol = n0 + wn * 64 + fr;
    float rs[4][4];
#pragma unroll
    for (int m = 0; m < 4; ++m)
#pragma unroll
        for (int q = 0; q < 4; ++q) rs[m][q] = 0.f;
#pragma unroll
    for (int n = 0; n < 4; ++n) {
        int col = ccol + n * 16;
        if (col >= N) continue;
#pragma unroll
        for (int m = 0; m < 4; ++m) {
#pragma unroll
            for (int q = 0; q < 4; ++q) {
                int row = crow + m * 16 + q;
                if (row < M) {
                    float e = __expf(acc[m][n][q]);
                    if (BF16OUT) {
                        unsigned u = __float_as_uint(e);
                        u += 0x7FFFu + ((u >> 16) & 1u);   // round-to-nearest-even bf16
                        Ch[(long)row * N + col] = (unsigned short)(u >> 16);
                    } else {
                        Cf[(long)row * N + col] = e;
                    }
                    rs[m][q] += e;
                }
            }
        }
    }
#pragma unroll
    for (int m = 0; m < 4; ++m)
#pragma unroll
        for (int q = 0; q < 4; ++q) {
            float v = rs[m][q];
            v += __shfl_xor(v, 1);
            v += __shfl_xor(v, 2);
            v += __shfl_xor(v, 4);
            v += __shfl_xor(v, 8);
            rs[m][q] = v;
        }
    if ((lane & 15) == 0) {
#pragma unroll
        for (int m = 0; m < 4; ++m)
#pragma unroll
            for (int q = 0; q < 4; ++q)
                rpart[wn][wm * 64 + (lane >> 4) * 4 + m * 16 + q] = rs[m][q];
    }
    __syncthreads();
    if (tid < 128) {
        int row = m0 + tid;
        if (row < M) psum[(long)nt * M + row] = rpart[0][tid] + rpart[1][tid];
    }
}

// ---------------------------------------------------------------- GRU recurrence + hidden preps
__device__ __forceinline__ float fd2(unsigned hv, unsigned wv, float acc) {
#if __has_builtin(__builtin_amdgcn_fdot2)
    return __builtin_amdgcn_fdot2(__builtin_bit_cast(h2, hv), __builtin_bit_cast(h2, wv), acc, false);
#else
    h2 a = __builtin_bit_cast(h2, hv), b = __builtin_bit_cast(h2, wv);
    return acc + (float)a.x * (float)b.x + (float)a.y * (float)b.y;
#endif
}

__global__ __launch_bounds__(256, 1) void k_gru(const float* __restrict__ gi,
                                                const float* __restrict__ whh,
                                                const float* __restrict__ bhh,
                                                ull* hbuf,
                                                f16* __restrict__ Hhi, f16* __restrict__ Hlo,
                                                const float* __restrict__ emb, f16* __restrict__ emb16,
                                                const float* __restrict__ enc, f16* __restrict__ ehi,
                                                f16* __restrict__ elo, f16* __restrict__ encT) {
    __shared__ ui4v wsvu[9216];               // [g][k8][u]: ((g*96+k8)*32+u), 147456 B
    __shared__ __align__(16) f16 hsf[768];
    __shared__ float part[2][8][32][3];
    const int tid = threadIdx.x;
    if (blockIdx.x >= 192) {
        // ---------- hidden prep on idle CUs ----------
        const long pt = (long)(blockIdx.x - 192) * 256 + tid;   // 0..16383
        const long n4 = (long)V_ * H_ / 4;
        for (long i = pt; i < n4; i += 64 * 256) {
            f32x4 v = ((const f32x4*)emb)[i];
            f16x4v r = {(f16)v.x, (f16)v.y, (f16)v.z, (f16)v.w};
            ((f16x4v*)emb16)[i] = r;
        }
        const long n4e = (long)B_ * S_ * H_ / 4;
        for (long i = pt; i < n4e; i += 64 * 256) {
            f32x4 v = ((const f32x4*)enc)[i];
            f16 h0 = (f16)v.x, h1 = (f16)v.y, h2v = (f16)v.z, h3 = (f16)v.w;
            f16x4v hv = {h0, h1, h2v, h3};
            ((f16x4v*)ehi)[i] = hv;
            f16x4v lv = {(f16)(v.x - (float)h0), (f16)(v.y - (float)h1),
                         (f16)(v.z - (float)h2v), (f16)(v.w - (float)h3)};
            ((f16x4v*)elo)[i] = lv;
        }
        // encT: s-innermost octets -> coalesced 16B writes; strided reads hit L2/L3
        const long nOct = 8L * 768 * 64;   // (b,h,s8)
        for (long o = pt; o < nOct; o += 64 * 256) {
            int s8 = (int)(o & 63);
            int h = (int)((o >> 6) % 768);
            int bb = (int)(o / (64 * 768));
            const float* sp = enc + ((long)bb * S_ + s8 * 8) * H_ + h;
            f16x8 r;
#pragma unroll
            for (int i = 0; i < 8; ++i) r[i] = (f16)sp[(long)i * H_];
            *(f16x8*)(encT + ((long)bb * H_ + h) * S_ + s8 * 8) = r;
        }
        return;
    }
    // ---------- recurrence ----------
    const int chain = blockIdx.x / 24;
    const int blk = blockIdx.x % 24;
    const int u0 = blk * 32;
    for (int idx = tid; idx < 9216; idx += 256) {
        int uu = idx & 31, k8 = (idx >> 5) % 96, g = idx / (96 * 32);
        const float* src = whh + (long)(g * H_ + u0 + uu) * H_ + k8 * 8;
        f32x4 a = *(const f32x4*)src;
        f32x4 b2 = *(const f32x4*)(src + 4);
        f16x8 pk = {(f16)a.x, (f16)a.y, (f16)a.z, (f16)a.w,
                    (f16)b2.x, (f16)b2.y, (f16)b2.z, (f16)b2.w};
        wsvu[idx] = __builtin_bit_cast(ui4v, pk);
    }
    float b_r = 0.f, b_z = 0.f, b_n = 0.f;
    if (tid < 32) {
        int c = u0 + tid;
        b_r = bhh[c];
        b_z = bhh[H_ + c];
        b_n = bhh[2 * H_ + c];
    }
    __syncthreads();
    const int u = tid & 31, q = tid >> 5, lane = tid & 63;
    const int pw = (tid >> 6) * 192 + lane;   // this wave's h-word base
    ui4v wreg[3][12];
#pragma unroll
    for (int g = 0; g < 3; ++g)
#pragma unroll
        for (int i = 0; i < 12; ++i)
            wreg[g][i] = wsvu[(g * 96 + q * 12 + i) * 32 + u];
    ull* base = hbuf + (long)chain * 1536;
    const bool fin = (tid < 32);
    float g0 = 0.f, g1 = 0.f, g2v = 0.f;
    if (fin) {
        const float* gp = gi + (long)chain * 270 * H3;
        int c = u0 + tid;
        g0 = gp[c];
        g1 = gp[H_ + c];
        g2v = gp[2 * H_ + c];
    }
    for (int s = 0; s < 270; ++s) {
        const ull* rb = base + (s & 1) * 768;
        ull* wb = base + ((s + 1) & 1) * 768;
        const unsigned want = (unsigned)s;
        ull v0, v1, v2, vh = 0;
        for (;;) {
            v0 = __hip_atomic_load(rb + pw, __ATOMIC_RELAXED, __HIP_MEMORY_SCOPE_AGENT);
            v1 = __hip_atomic_load(rb + pw + 64, __ATOMIC_RELAXED, __HIP_MEMORY_SCOPE_AGENT);
            v2 = __hip_atomic_load(rb + pw + 128, __ATOMIC_RELAXED, __HIP_MEMORY_SCOPE_AGENT);
            bool ok = ((unsigned)(v0 >> 32) == want) & ((unsigned)(v1 >> 32) == want) &
                      ((unsigned)(v2 >> 32) == want);
            if (fin) {
                vh = __hip_atomic_load(rb + u0 + tid, __ATOMIC_RELAXED, __HIP_MEMORY_SCOPE_AGENT);
                ok &= ((unsigned)(vh >> 32) == want);
            }
            if (ok) break;
        }
        hsf[pw] = (f16)__uint_as_float((unsigned)v0);
        hsf[pw + 64] = (f16)__uint_as_float((unsigned)v1);
        hsf[pw + 128] = (f16)__uint_as_float((unsigned)v2);
        __builtin_amdgcn_wave_barrier();
        float ar = 0.f, az = 0.f, an = 0.f;
#pragma unroll
        for (int i = 0; i < 12; ++i) {
            ui4v hv = *(const ui4v*)(&hsf[(q * 12 + i) * 8]);
            ui4v wr = wreg[0][i], wz = wreg[1][i], wn = wreg[2][i];
            ar = fd2(hv.x, wr.x, ar); ar = fd2(hv.y, wr.y, ar);
            ar = fd2(hv.z, wr.z, ar); ar = fd2(hv.w, wr.w, ar);
            az = fd2(hv.x, wz.x, az); az = fd2(hv.y, wz.y, az);
            az = fd2(hv.z, wz.z, az); az = fd2(hv.w, wz.w, az);
            an = fd2(hv.x, wn.x, an); an = fd2(hv.y, wn.y, an);
            an = fd2(hv.z, wn.z, an); an = fd2(hv.w, wn.w, an);
        }
        const int par = s & 1;
        part[par][q][u][0] = ar;
        part[par][q][u][1] = az;
        part[par][q][u][2] = an;
        __syncthreads();                       // B: partials ready (block-wide)
        if (fin) {
            float gr = b_r, gz = b_z, gn = b_n;
#pragma unroll
            for (int qq = 0; qq < 8; ++qq) {
                gr += part[par][qq][tid][0];
                gz += part[par][qq][tid][1];
                gn += part[par][qq][tid][2];
            }
            float hold = __uint_as_float((unsigned)vh);
            float rg = 1.f / (1.f + expf(-(g0 + gr)));
            float zg = 1.f / (1.f + expf(-(g1 + gz)));
            float ng = tanhf(g2v + rg * gn);
            float hnew = (1.f - zg) * ng + zg * hold;
            int c = u0 + tid;
            ull wvv = ((ull)(unsigned)(s + 1) << 32) | (ull)__float_as_uint(hnew);
            __hip_atomic_store(wb + c, wvv, __ATOMIC_RELAXED, __HIP_MEMORY_SCOPE_AGENT);
            long row = (long)chain * 270 + s;
            f16 h16 = (f16)hnew;
            Hhi[row * H_ + c] = h16;
            Hlo[row * H_ + c] = (f16)(hnew - (float)h16);
            if (s < 269) {   // prefetch next step's gi
                const float* gp = gi + ((long)chain * 270 + s + 1) * H3;
                g0 = gp[c];
                g1 = gp[H_ + c];
                g2v = gp[2 * H_ + c];
            }
        }
    }
}

// ---------------------------------------------------------------- attention softmax
__global__ __launch_bounds__(256) void k_attn_softmax(const float* __restrict__ lg,
                                                      const int* __restrict__ x, f16* __restrict__ ah) {
    __shared__ float red[256];
    int r = blockIdx.x, tid = threadIdx.x;
    int b = r / 270;
    const float* lr = lg + (long)r * S_;
    const int* xb = x + (long)b * S_;
    float v0 = lr[tid];
    if (xb[tid] == 0) v0 = -1e9f;
    float v1 = lr[tid + 256];
    if (xb[tid + 256] == 0) v1 = -1e9f;
    red[tid] = fmaxf(v0, v1);
    __syncthreads();
    for (int o = 128; o > 0; o >>= 1) {
        if (tid < o) red[tid] = fmaxf(red[tid], red[tid + o]);
        __syncthreads();
    }
    float m = red[0];
    __syncthreads();
    float e0 = __expf(v0 - m), e1 = __expf(v1 - m);
    red[tid] = e0 + e1;
    __syncthreads();
    for (int o = 128; o > 0; o >>= 1) {
        if (tid < o) red[tid] += red[tid + o];
        __syncthreads();
    }
    float inv = 1.f / red[0];
    ah[(long)r * S_ + tid] = (f16)(e0 * inv);
    ah[(long)r * S_ + tid + 256] = (f16)(e1 * inv);
}

// ---------------------------------------------------------------- p_gen
__global__ __launch_bounds__(256) void k_pgen(const f16* __restrict__ Wall, const f16* __restrict__ Hhi,
                                              const f16* __restrict__ Hlo, const float* __restrict__ ctx,
                                              const float* __restrict__ wg, const float* __restrict__ wgb,
                                              float* __restrict__ pg) {
    __shared__ float red[256];
    int r = blockIdx.x, tid = threadIdx.x;
    float a = 0.f;
    for (int i = tid; i < H_; i += 256) {
        a += (float)Wall[(long)r * H_ + i] * wg[i];
        a += ((float)Hhi[(long)r * H_ + i] + (float)Hlo[(long)r * H_ + i]) * wg[H_ + i];
        a += ctx[(long)r * H_ + i] * wg[2 * H_ + i];
    }
    red[tid] = a;
    __syncthreads();
    for (int o = 128; o > 0; o >>= 1) {
        if (tid < o) red[tid] += red[tid + o];
        __syncthreads();
    }
    if (tid == 0) pg[r] = 1.f / (1.f + expf(-(red[0] + wgb[0])));
}

// ---------------------------------------------------------------- rowsum reduce: rinv = 1/sum_b psum[b][r]
__global__ void k_redsum(const float* __restrict__ psum, float* __restrict__ rinv, int nb) {
    int r = blockIdx.x * 256 + threadIdx.x;
    if (r >= R_) return;
    float s = 0.f;
    for (int b = 0; b < nb; ++b) s += psum[(long)b * R_ + r];
    rinv[r] = 1.f / s;
}

// ---------------------------------------------------------------- fused finalize+scatter (bf16 path)
// One block per row: LDS row image = pg*rinv*exp; scatter adds via LDS atomics;
// stream f32 row to out once.
__global__ __launch_bounds__(256, 1) void k_fin2(const unsigned short* __restrict__ expv,
                                                 const float* __restrict__ rinv,
                                                 const float* __restrict__ pg,
                                                 const f16* __restrict__ ah,
                                                 const int* __restrict__ x,
                                                 float* __restrict__ out) {
    __shared__ float row[V_];
    const int r = blockIdx.x, tid = threadIdx.x;
    const int b = r / 270;
    const float pgv = pg[r];
    const float scale = pgv * rinv[r];
    const unsigned short* ep = expv + (long)r * V_;
    for (int i = tid; i < V_ / 4; i += 256) {
        u16x4 v = ((const u16x4*)ep)[i];
        f32x4 o;
        o.x = __uint_as_float((unsigned)v.x << 16) * scale;
        o.y = __uint_as_float((unsigned)v.y << 16) * scale;
        o.z = __uint_as_float((unsigned)v.z << 16) * scale;
        o.w = __uint_as_float((unsigned)v.w << 16) * scale;
        ((f32x4*)row)[i] = o;
    }
    __syncthreads();
    const float om = 1.f - pgv;
    for (int s = tid; s < S_; s += 256) {
        int xv = x[(long)b * S_ + s];
        if (xv != 0) {
            float a = (float)ah[(long)r * S_ + s];
            if (a != 0.f) atomicAdd(&row[xv], om * a);
        }
    }
    __syncthreads();
    float* orow = out + (long)r * V_;
    for (int i = tid; i < V_ / 4; i += 256)
        ((f32x4*)orow)[i] = ((const f32x4*)row)[i];
}

// ---------------------------------------------------------------- fallback finalize + scatter
__global__ __launch_bounds__(256) void k_final(float* __restrict__ out, const float* __restrict__ rinv,
                                               const float* __restrict__ pg) {
    int r = blockIdx.y;
    int i = blockIdx.x * 256 + threadIdx.x;
    if (i >= V_ / 4) return;
    float scale = pg[r] * rinv[r];
    f32x4* po = (f32x4*)(out + (long)r * V_);
    f32x4 v = po[i];
    v.x *= scale;
    v.y *= scale;
    v.z *= scale;
    v.w *= scale;
    po[i] = v;
}

__global__ __launch_bounds__(512) void k_scatter(float* __restrict__ out, const f16* __restrict__ ah,
                                                 const float* __restrict__ pg, const int* __restrict__ x) {
    int r = blockIdx.x, s = threadIdx.x;
    int b = r / 270;
    int xv = x[(long)b * S_ + s];
    if (xv == 0) return;
    float a = (float)ah[(long)r * S_ + s];
    if (a == 0.f) return;
    atomicAdd(out + (long)r * V_ + xv, (1.f - pg[r]) * a);
}

// ---------------------------------------------------------------- host
extern "C" void kernel_launch(void* const* d_in, const int* in_sizes, int n_in, void* d_out,
                              int out_size, void* d_ws, size_t ws_size, hipStream_t stream) {
    (void)in_sizes; (void)n_in; (void)out_size;
    const int* x = (const int*)d_in[0];
    const float* dec = (const float*)d_in[1];
    const float* enc = (const float*)d_in[2];
    const float* hid = (const float*)d_in[3];
    const int* tea = (const int*)d_in[4];
    const float* emb = (const float*)d_in[6];
    const float* wih = (const float*)d_in[7];
    const float* whh = (const float*)d_in[8];
    const float* bih = (const float*)d_in[9];
    const float* bhh = (const float*)d_in[10];
    const float* wgw = (const float*)d_in[11];
    const float* wgb = (const float*)d_in[12];
    float* out = (float*)d_out;

    char* w = (char*)d_ws;
    size_t off = 0;
    auto alloc = [&](size_t bytes) {
        void* p = w + off;
        off = (off + bytes + 255) & ~(size_t)255;
        return p;
    };
    ull* hbuf = (ull*)alloc(8 * 1536 * 8);          // [chain][parity][768] seq-tagged h
    f16* Wall = (f16*)alloc((size_t)R_ * H_ * 2);
    f16* wih16 = (f16*)alloc((size_t)H3 * H_ * 2);
    float* giA = (float*)alloc((size_t)R_ * H3 * 4);
    f16* Hhi = (f16*)alloc((size_t)R_ * H_ * 2);
    f16* Hlo = (f16*)alloc((size_t)R_ * H_ * 2);
    f16* emb16 = (f16*)alloc((size_t)V_ * H_ * 2);
    f16* ehi = (f16*)alloc((size_t)B_ * S_ * H_ * 2);
    f16* elo = (f16*)alloc((size_t)B_ * S_ * H_ * 2);
    f16* encT = (f16*)alloc((size_t)B_ * H_ * S_ * 2);
    float* lgH = (float*)alloc((size_t)R_ * S_ * 4);
    f16* ah = (f16*)alloc((size_t)R_ * S_ * 2);
    float* ctx = (float*)alloc((size_t)R_ * H_ * 4);
    float* pg = (float*)alloc(R_ * 4);
    float* psum = (float*)alloc((size_t)VNT * R_ * 4);
    float* rinv = (float*)alloc(R_ * 4);
    unsigned short* expv = (unsigned short*)alloc((size_t)R_ * V_ * 2);
    const bool fused = (off <= ws_size);            // bf16-exp path fits in ws?

    const int nH = 8 * 1536 * 2;                    // hbuf as ints
    k_zero<<<(nH + 255) / 256, 256, 0, stream>>>((int*)hbuf, nH);
    k_cast<<<512, 256, 0, stream>>>(wih, wih16, (long)H3 * H_);
    k_build_wall<<<R_, 256, 0, stream>>>(emb, dec, tea, Wall);
    k_init_h<<<24, 256, 0, stream>>>(hid, hbuf);

    // gi = W_all @ w_ih^T + b_ih
    {
        dim3 g(H3 / 128, (R_ + 127) / 128, 1);
        k_gemm<1><<<g, 256, 0, stream>>>(Wall, wih16, giA, bih, R_, H3, H_, 0, 0, 0);
    }
    // recurrence (blocks 0-191) + hidden preps on idle CUs (blocks 192-255)
    k_gru<<<256, 256, 0, stream>>>(giA, whh, bhh, hbuf, Hhi, Hlo,
                                   emb, emb16, enc, ehi, elo, encT);

    // attention logits (merged hi/lo): Hhi*Ehi + Hhi*Elo + Hlo*Ehi
    {
        dim3 g(S_ / 128, 3, 8);
        k_attn3<<<g, 256, 0, stream>>>(Hhi, Hlo, ehi, elo, lgH, 270, S_, H_,
                                       270L * H_, (long)S_ * H_, 270L * S_);
    }
    k_attn_softmax<<<R_, 256, 0, stream>>>(lgH, x, ah);
    {
        dim3 g(H_ / 128, 3, 8);
        k_gemm<0><<<g, 256, 0, stream>>>(ah, encT, ctx, nullptr, 270, H_, S_, 270L * S_, (long)H_ * S_, 270L * H_);
    }
    k_pgen<<<R_, 256, 0, stream>>>(Wall, Hhi, Hlo, ctx, wgw, wgb, pg);

    if (fused) {
        k_vocab<1><<<VMT * VNT, 256, 0, stream>>>(Hhi, emb16, nullptr, expv, psum);
        k_redsum<<<(R_ + 255) / 256, 256, 0, stream>>>(psum, rinv, VNT);
        k_fin2<<<R_, 256, 0, stream>>>(expv, rinv, pg, ah, x, out);
    } else {
        k_vocab<0><<<VMT * VNT, 256, 0, stream>>>(Hhi, emb16, out, nullptr, psum);
        k_redsum<<<(R_ + 255) / 256, 256, 0, stream>>>(psum, rinv, VNT);
        dim3 g((V_ / 4 + 255) / 256, R_, 1);
        k_final<<<g, 256, 0, stream>>>(out, rinv, pg);
        k_scatter<<<R_, 512, 0, stream>>>(out, ah, pg, x);
    }
}

// Round 12
// 1117.160 us; speedup vs baseline: 1.0153x; 1.0153x over previous
//
#include <hip/hip_runtime.h>
#include <hip/hip_bf16.h>

typedef _Float16 f16;
typedef _Float16 f16x8 __attribute__((ext_vector_type(8)));
typedef _Float16 f16x4v __attribute__((ext_vector_type(4)));
typedef _Float16 h2 __attribute__((ext_vector_type(2)));
typedef float f32x4 __attribute__((ext_vector_type(4)));
typedef unsigned ui4v __attribute__((ext_vector_type(4)));
typedef unsigned long long ull;

#define B_ 8
#define S_ 512
#define H_ 768
#define V_ 35004
#define J_ 30
#define K_ 9
#define R_ 2160          // B*J*K rows, row r = b*270 + j*9 + t  (matches out layout)
#define H3 2304
#define VMT 17           // vocab M tiles
#define VNT 274          // vocab N tiles

// ---------------------------------------------------------------- prep kernels

__global__ void k_zero(int* p, int n) {
    int i = blockIdx.x * 256 + threadIdx.x;
    if (i < n) p[i] = 0;
}

__global__ void k_cast(const float* __restrict__ s, f16* __restrict__ d, long n) {
    for (long i = (long)blockIdx.x * 256 + threadIdx.x; i < n; i += (long)gridDim.x * 256)
        d[i] = (f16)s[i];
}

// W_all[r] = (t==0) ? decoder_input[b,j,:] : embed[teacher[b,j,t-1],:]
__global__ void k_build_wall(const float* __restrict__ emb, const float* __restrict__ dec,
                             const int* __restrict__ teacher, f16* __restrict__ Wall) {
    int r = blockIdx.x;
    int b = r / 270, s = r % 270, j = s / 9, t = s % 9;
    const float* src = (t == 0) ? dec + ((long)b * J_ + j) * H_
                                : emb + (long)teacher[((long)b * J_ + j) * K_ + (t - 1)] * H_;
    f16* dst = Wall + (long)r * H_;
    for (int c = threadIdx.x; c < H_; c += 256) dst[c] = (f16)src[c];
}

// h exchange word: {seq:32 | f32 bits:32}; chain-major [chain][parity][768]
__global__ void k_init_h(const float* __restrict__ hidden, ull* __restrict__ hbuf) {
    int i = blockIdx.x * 256 + threadIdx.x;
    if (i < B_ * H_) {
        int b = i / H_, u = i % H_;
        hbuf[(long)b * 1536 + u] = (ull)__float_as_uint(hidden[i]);  // seq 0, parity 0
    }
}

// ---------------------------------------------------------------- shared GEMM helpers
typedef const __attribute__((address_space(1))) unsigned GASU;
typedef __attribute__((address_space(3))) unsigned LASU;
__device__ __forceinline__ void gld16(const f16* g, f16* l) {
    __builtin_amdgcn_global_load_lds((GASU*)g, (LASU*)l, 16, 0, 0);
}

// ---------------------------------------------------------------- f16 MFMA GEMM (m97 structure)
// C[M,N] = A[M,K] @ B[N,K]^T ; MODE 0: store, 1: store + bias[col]
template <int MODE>
__global__ __launch_bounds__(256) void k_gemm(const f16* __restrict__ A, const f16* __restrict__ Bm,
                                              float* __restrict__ C, const float* __restrict__ bias,
                                              int M, int N, int K, long sA, long sB, long sC) {
    A += (long)blockIdx.z * sA;
    Bm += (long)blockIdx.z * sB;
    C += (long)blockIdx.z * sC;
    const int m0 = blockIdx.y * 128, n0 = blockIdx.x * 128;
    __shared__ f16 As[128 * 32];
    __shared__ f16 Bs[128 * 32];
    const int tid = threadIdx.x, lane = tid & 63, wave = tid >> 6;
    const int wm = wave >> 1, wn = wave & 1;
    const int fr = lane & 15, kg = lane >> 4;
    f32x4 acc[4][4] = {};
    const int idxu = wave * 128;
    const int i0 = idxu + lane, i1 = idxu + 64 + lane;
    const int r0 = i0 >> 2, k80 = i0 & 3;
    const int r1 = i1 >> 2, k81 = i1 & 3;
    int ga0 = m0 + r0; if (ga0 >= M) ga0 = M - 1;
    int ga1 = m0 + r1; if (ga1 >= M) ga1 = M - 1;
    int gb0 = n0 + r0; if (gb0 >= N) gb0 = N - 1;
    int gb1 = n0 + r1; if (gb1 >= N) gb1 = N - 1;
    const f16* pa0 = A + (long)ga0 * K + k80 * 8;
    const f16* pa1 = A + (long)ga1 * K + k81 * 8;
    const f16* pb0 = Bm + (long)gb0 * K + k80 * 8;
    const f16* pb1 = Bm + (long)gb1 * K + k81 * 8;
    for (int kt = 0; kt < K; kt += 32) {
        gld16(pa0 + kt, As + idxu * 8);
        gld16(pa1 + kt, As + idxu * 8 + 512);
        gld16(pb0 + kt, Bs + idxu * 8);
        gld16(pb1 + kt, Bs + idxu * 8 + 512);
        __syncthreads();
        f16x8 af[4], bf[4];
#pragma unroll
        for (int m = 0; m < 4; ++m) af[m] = *(const f16x8*)(As + (wm * 64 + m * 16 + fr) * 32 + kg * 8);
#pragma unroll
        for (int n = 0; n < 4; ++n) bf[n] = *(const f16x8*)(Bs + (wn * 64 + n * 16 + fr) * 32 + kg * 8);
#pragma unroll
        for (int m = 0; m < 4; ++m)
#pragma unroll
            for (int n = 0; n < 4; ++n)
                acc[m][n] = __builtin_amdgcn_mfma_f32_16x16x32_f16(af[m], bf[n], acc[m][n], 0, 0, 0);
        __syncthreads();
    }
    const int crow = m0 + wm * 64 + (lane >> 4) * 4;
    const int ccol = n0 + wn * 64 + fr;
#pragma unroll
    for (int n = 0; n < 4; ++n) {
        int col = ccol + n * 16;
        if (col >= N) continue;
        float bv = (MODE == 1) ? bias[col] : 0.f;
#pragma unroll
        for (int m = 0; m < 4; ++m) {
#pragma unroll
            for (int q = 0; q < 4; ++q) {
                int row = crow + m * 16 + q;
                if (row < M) C[(long)row * N + col] = acc[m][n][q] + bv;
            }
        }
    }
}

// ---------------------------------------------------------------- merged hi/lo attention logits
__global__ __launch_bounds__(256) void k_attn3(const f16* __restrict__ Ahi, const f16* __restrict__ Alo,
                                               const f16* __restrict__ Bhi, const f16* __restrict__ Blo,
                                               float* __restrict__ C, int M, int N, int K,
                                               long sA, long sB, long sC) {
    const long za = (long)blockIdx.z * sA, zb = (long)blockIdx.z * sB;
    C += (long)blockIdx.z * sC;
    const int m0 = blockIdx.y * 128, n0 = blockIdx.x * 128;
    __shared__ f16 As[128 * 32];
    __shared__ f16 Bs[128 * 32];
    const int tid = threadIdx.x, lane = tid & 63, wave = tid >> 6;
    const int wm = wave >> 1, wn = wave & 1;
    const int fr = lane & 15, kg = lane >> 4;
    f32x4 acc[4][4] = {};
    const int idxu = wave * 128;
    const int i0 = idxu + lane, i1 = idxu + 64 + lane;
    const int r0 = i0 >> 2, k80 = i0 & 3;
    const int r1 = i1 >> 2, k81 = i1 & 3;
    int ga0 = m0 + r0; if (ga0 >= M) ga0 = M - 1;
    int ga1 = m0 + r1; if (ga1 >= M) ga1 = M - 1;
    int gb0 = n0 + r0; if (gb0 >= N) gb0 = N - 1;
    int gb1 = n0 + r1; if (gb1 >= N) gb1 = N - 1;
    const long oa0 = (long)ga0 * K + k80 * 8, oa1 = (long)ga1 * K + k81 * 8;
    const long ob0 = (long)gb0 * K + k80 * 8, ob1 = (long)gb1 * K + k81 * 8;
    for (int ph = 0; ph < 3; ++ph) {
        const f16* Ap = (ph == 2 ? Alo : Ahi) + za;
        const f16* Bp = (ph == 1 ? Blo : Bhi) + zb;
        for (int kt = 0; kt < K; kt += 32) {
            gld16(Ap + oa0 + kt, As + idxu * 8);
            gld16(Ap + oa1 + kt, As + idxu * 8 + 512);
            gld16(Bp + ob0 + kt, Bs + idxu * 8);
            gld16(Bp + ob1 + kt, Bs + idxu * 8 + 512);
            __syncthreads();
            f16x8 af[4], bf[4];
#pragma unroll
            for (int m = 0; m < 4; ++m) af[m] = *(const f16x8*)(As + (wm * 64 + m * 16 + fr) * 32 + kg * 8);
#pragma unroll
            for (int n = 0; n < 4; ++n) bf[n] = *(const f16x8*)(Bs + (wn * 64 + n * 16 + fr) * 32 + kg * 8);
#pragma unroll
            for (int m = 0; m < 4; ++m)
#pragma unroll
                for (int n = 0; n < 4; ++n)
                    acc[m][n] = __builtin_amdgcn_mfma_f32_16x16x32_f16(af[m], bf[n], acc[m][n], 0, 0, 0);
            __syncthreads();
        }
    }
    const int crow = m0 + wm * 64 + (lane >> 4) * 4;
    const int ccol = n0 + wn * 64 + fr;
#pragma unroll
    for (int n = 0; n < 4; ++n) {
        int col = ccol + n * 16;
        if (col >= N) continue;
#pragma unroll
        for (int m = 0; m < 4; ++m) {
#pragma unroll
            for (int q = 0; q < 4; ++q) {
                int row = crow + m * 16 + q;
                if (row < M) C[(long)row * N + col] = acc[m][n][q];
            }
        }
    }
}

// ---------------------------------------------------------------- vocab GEMM: out=exp(Hhi@emb^T)+psum
__global__ __launch_bounds__(256) void k_vocab(const f16* __restrict__ A, const f16* __restrict__ Bm,
                                               float* __restrict__ C, float* __restrict__ psum) {
    const int M = R_, N = V_, K = H_;
    const int nwg = VMT * VNT;
    int lin = blockIdx.x;
    int q8 = nwg / 8, r8 = nwg % 8;
    int xcd = lin & 7, idx = lin >> 3;
    int newlin = (xcd < r8) ? xcd * (q8 + 1) + idx : r8 * (q8 + 1) + (xcd - r8) * q8 + idx;
    int mt = newlin % VMT, nt = newlin / VMT;
    const int m0 = mt * 128, n0 = nt * 128;
    __shared__ f16 As[128 * 32];
    __shared__ f16 Bs[128 * 32];
    __shared__ float rpart[2][128];
    const int tid = threadIdx.x, lane = tid & 63, wave = tid >> 6;
    const int wm = wave >> 1, wn = wave & 1;
    const int fr = lane & 15, kg = lane >> 4;
    f32x4 acc[4][4] = {};
    const int idxu = wave * 128;
    const int i0 = idxu + lane, i1 = idxu + 64 + lane;
    const int r0 = i0 >> 2, k80 = i0 & 3;
    const int r1 = i1 >> 2, k81 = i1 & 3;
    int ga0 = m0 + r0; if (ga0 >= M) ga0 = M - 1;
    int ga1 = m0 + r1; if (ga1 >= M) ga1 = M - 1;
    int gb0 = n0 + r0; if (gb0 >= N) gb0 = N - 1;
    int gb1 = n0 + r1; if (gb1 >= N) gb1 = N - 1;
    const f16* pa0 = A + (long)ga0 * K + k80 * 8;
    const f16* pa1 = A + (long)ga1 * K + k81 * 8;
    const f16* pb0 = Bm + (long)gb0 * K + k80 * 8;
    const f16* pb1 = Bm + (long)gb1 * K + k81 * 8;
    for (int kt = 0; kt < K; kt += 32) {
        gld16(pa0 + kt, As + idxu * 8);
        gld16(pa1 + kt, As + idxu * 8 + 512);
        gld16(pb0 + kt, Bs + idxu * 8);
        gld16(pb1 + kt, Bs + idxu * 8 + 512);
        __syncthreads();
        f16x8 af[4], bf[4];
#pragma unroll
        for (int m = 0; m < 4; ++m) af[m] = *(const f16x8*)(As + (wm * 64 + m * 16 + fr) * 32 + kg * 8);
#pragma unroll
        for (int n = 0; n < 4; ++n) bf[n] = *(const f16x8*)(Bs + (wn * 64 + n * 16 + fr) * 32 + kg * 8);
#pragma unroll
        for (int m = 0; m < 4; ++m)
#pragma unroll
            for (int n = 0; n < 4; ++n)
                acc[m][n] = __builtin_amdgcn_mfma_f32_16x16x32_f16(af[m], bf[n], acc[m][n], 0, 0, 0);
        __syncthreads();
    }
    const int crow = m0 + wm * 64 + (lane >> 4) * 4;
    const int ccol = n0 + wn * 64 + fr;
    float rs[4][4];
#pragma unroll
    for (int m = 0; m < 4; ++m)
#pragma unroll
        for (int q = 0; q < 4; ++q) rs[m][q] = 0.f;
#pragma unroll
    for (int n = 0; n < 4; ++n) {
        int col = ccol + n * 16;
        if (col >= N) continue;
#pragma unroll
        for (int m = 0; m < 4; ++m) {
#pragma unroll
            for (int q = 0; q < 4; ++q) {
                int row = crow + m * 16 + q;
                if (row < M) {
                    float e = __expf(acc[m][n][q]);
                    C[(long)row * N + col] = e;
                    rs[m][q] += e;
                }
            }
        }
    }
#pragma unroll
    for (int m = 0; m < 4; ++m)
#pragma unroll
        for (int q = 0; q < 4; ++q) {
            float v = rs[m][q];
            v += __shfl_xor(v, 1);
            v += __shfl_xor(v, 2);
            v += __shfl_xor(v, 4);
            v += __shfl_xor(v, 8);
            rs[m][q] = v;
        }
    if ((lane & 15) == 0) {
#pragma unroll
        for (int m = 0; m < 4; ++m)
#pragma unroll
            for (int q = 0; q < 4; ++q)
                rpart[wn][wm * 64 + (lane >> 4) * 4 + m * 16 + q] = rs[m][q];
    }
    __syncthreads();
    if (tid < 128) {
        int row = m0 + tid;
        if (row < M) psum[(long)nt * M + row] = rpart[0][tid] + rpart[1][tid];
    }
}

// ---------------------------------------------------------------- GRU recurrence + hidden preps
__device__ __forceinline__ float fd2(unsigned hv, unsigned wv, float acc) {
#if __has_builtin(__builtin_amdgcn_fdot2)
    return __builtin_amdgcn_fdot2(__builtin_bit_cast(h2, hv), __builtin_bit_cast(h2, wv), acc, false);
#else
    h2 a = __builtin_bit_cast(h2, hv), b = __builtin_bit_cast(h2, wv);
    return acc + (float)a.x * (float)b.x + (float)a.y * (float)b.y;
#endif
}

__global__ __launch_bounds__(256, 1) void k_gru(const float* __restrict__ gi,
                                                const float* __restrict__ whh,
                                                const float* __restrict__ bhh,
                                                ull* hbuf,
                                                f16* __restrict__ Hhi, f16* __restrict__ Hlo,
                                                const float* __restrict__ emb, f16* __restrict__ emb16,
                                                const float* __restrict__ enc, f16* __restrict__ ehi,
                                                f16* __restrict__ elo, f16* __restrict__ encT) {
    __shared__ ui4v wsvu[9216];               // [g][k8][u]: ((g*96+k8)*32+u), 147456 B
    __shared__ __align__(16) f16 hsf[768];
    __shared__ float part[2][8][32][3];
    const int tid = threadIdx.x;
    if (blockIdx.x >= 192) {
        // ---------- hidden prep on idle CUs ----------
        const long pt = (long)(blockIdx.x - 192) * 256 + tid;   // 0..16383
        const long n4 = (long)V_ * H_ / 4;
        for (long i = pt; i < n4; i += 64 * 256) {
            f32x4 v = ((const f32x4*)emb)[i];
            f16x4v r = {(f16)v.x, (f16)v.y, (f16)v.z, (f16)v.w};
            ((f16x4v*)emb16)[i] = r;
        }
        const long n4e = (long)B_ * S_ * H_ / 4;
        for (long i = pt; i < n4e; i += 64 * 256) {
            f32x4 v = ((const f32x4*)enc)[i];
            f16 h0 = (f16)v.x, h1 = (f16)v.y, h2v = (f16)v.z, h3 = (f16)v.w;
            f16x4v hv = {h0, h1, h2v, h3};
            ((f16x4v*)ehi)[i] = hv;
            f16x4v lv = {(f16)(v.x - (float)h0), (f16)(v.y - (float)h1),
                         (f16)(v.z - (float)h2v), (f16)(v.w - (float)h3)};
            ((f16x4v*)elo)[i] = lv;
        }
        // encT via LDS-tiled transpose (64x64 f32 tile, pad 65): coalesced both sides
        float* tl = (float*)wsvu;           // 64*65*4 = 16.6 KB of the prep block's LDS
        for (int t = blockIdx.x - 192; t < 8 * 8 * 12; t += 64) {
            int ht = t % 12, st = (t / 12) % 8, bb = t / 96;
            __syncthreads();
#pragma unroll
            for (int k = 0; k < 16; ++k) {
                int i = tid + k * 256;
                int sl = i >> 6, hl = i & 63;
                tl[sl * 65 + hl] = enc[((long)bb * S_ + st * 64 + sl) * H_ + ht * 64 + hl];
            }
            __syncthreads();
#pragma unroll
            for (int k = 0; k < 16; ++k) {
                int i = tid + k * 256;
                int hl = i >> 6, sl = i & 63;
                encT[((long)bb * H_ + ht * 64 + hl) * S_ + st * 64 + sl] = (f16)tl[sl * 65 + hl];
            }
        }
        return;
    }
    // ---------- recurrence ----------
    const int chain = blockIdx.x / 24;
    const int blk = blockIdx.x % 24;
    const int u0 = blk * 32;
    for (int idx = tid; idx < 9216; idx += 256) {
        int uu = idx & 31, k8 = (idx >> 5) % 96, g = idx / (96 * 32);
        const float* src = whh + (long)(g * H_ + u0 + uu) * H_ + k8 * 8;
        f32x4 a = *(const f32x4*)src;
        f32x4 b2 = *(const f32x4*)(src + 4);
        f16x8 pk = {(f16)a.x, (f16)a.y, (f16)a.z, (f16)a.w,
                    (f16)b2.x, (f16)b2.y, (f16)b2.z, (f16)b2.w};
        wsvu[idx] = __builtin_bit_cast(ui4v, pk);
    }
    float b_r = 0.f, b_z = 0.f, b_n = 0.f;
    if (tid < 32) {
        int c = u0 + tid;
        b_r = bhh[c];
        b_z = bhh[H_ + c];
        b_n = bhh[2 * H_ + c];
    }
    __syncthreads();
    const int u = tid & 31, q = tid >> 5, lane = tid & 63;
    const int pw = (tid >> 6) * 192 + lane;   // this wave's h-word base
    ui4v wreg[3][12];
#pragma unroll
    for (int g = 0; g < 3; ++g)
#pragma unroll
        for (int i = 0; i < 12; ++i)
            wreg[g][i] = wsvu[(g * 96 + q * 12 + i) * 32 + u];
    ull* base = hbuf + (long)chain * 1536;
    const bool fin = (tid < 32);
    float g0 = 0.f, g1 = 0.f, g2v = 0.f;
    if (fin) {
        const float* gp = gi + (long)chain * 270 * H3;
        int c = u0 + tid;
        g0 = gp[c];
        g1 = gp[H_ + c];
        g2v = gp[2 * H_ + c];
    }
    for (int s = 0; s < 270; ++s) {
        const ull* rb = base + (s & 1) * 768;
        ull* wb = base + ((s + 1) & 1) * 768;
        const unsigned want = (unsigned)s;
        ull v0, v1, v2, vh = 0;
        for (;;) {
            v0 = __hip_atomic_load(rb + pw, __ATOMIC_RELAXED, __HIP_MEMORY_SCOPE_AGENT);
            v1 = __hip_atomic_load(rb + pw + 64, __ATOMIC_RELAXED, __HIP_MEMORY_SCOPE_AGENT);
            v2 = __hip_atomic_load(rb + pw + 128, __ATOMIC_RELAXED, __HIP_MEMORY_SCOPE_AGENT);
            bool ok = ((unsigned)(v0 >> 32) == want) & ((unsigned)(v1 >> 32) == want) &
                      ((unsigned)(v2 >> 32) == want);
            if (fin) {
                vh = __hip_atomic_load(rb + u0 + tid, __ATOMIC_RELAXED, __HIP_MEMORY_SCOPE_AGENT);
                ok &= ((unsigned)(vh >> 32) == want);
            }
            if (ok) break;
        }
        hsf[pw] = (f16)__uint_as_float((unsigned)v0);
        hsf[pw + 64] = (f16)__uint_as_float((unsigned)v1);
        hsf[pw + 128] = (f16)__uint_as_float((unsigned)v2);
        __builtin_amdgcn_wave_barrier();
        float ar = 0.f, az = 0.f, an = 0.f;
#pragma unroll
        for (int i = 0; i < 12; ++i) {
            ui4v hv = *(const ui4v*)(&hsf[(q * 12 + i) * 8]);
            ui4v wr = wreg[0][i], wz = wreg[1][i], wn = wreg[2][i];
            ar = fd2(hv.x, wr.x, ar); ar = fd2(hv.y, wr.y, ar);
            ar = fd2(hv.z, wr.z, ar); ar = fd2(hv.w, wr.w, ar);
            az = fd2(hv.x, wz.x, az); az = fd2(hv.y, wz.y, az);
            az = fd2(hv.z, wz.z, az); az = fd2(hv.w, wz.w, az);
            an = fd2(hv.x, wn.x, an); an = fd2(hv.y, wn.y, an);
            an = fd2(hv.z, wn.z, an); an = fd2(hv.w, wn.w, an);
        }
        const int par = s & 1;
        part[par][q][u][0] = ar;
        part[par][q][u][1] = az;
        part[par][q][u][2] = an;
        __syncthreads();                       // B: partials ready (block-wide)
        if (fin) {
            float gr = b_r, gz = b_z, gn = b_n;
#pragma unroll
            for (int qq = 0; qq < 8; ++qq) {
                gr += part[par][qq][tid][0];
                gz += part[par][qq][tid][1];
                gn += part[par][qq][tid][2];
            }
            float hold = __uint_as_float((unsigned)vh);
            float rg = 1.f / (1.f + expf(-(g0 + gr)));
            float zg = 1.f / (1.f + expf(-(g1 + gz)));
            float ng = tanhf(g2v + rg * gn);
            float hnew = (1.f - zg) * ng + zg * hold;
            int c = u0 + tid;
            ull wvv = ((ull)(unsigned)(s + 1) << 32) | (ull)__float_as_uint(hnew);
            __hip_atomic_store(wb + c, wvv, __ATOMIC_RELAXED, __HIP_MEMORY_SCOPE_AGENT);
            long row = (long)chain * 270 + s;
            f16 h16 = (f16)hnew;
            Hhi[row * H_ + c] = h16;
            Hlo[row * H_ + c] = (f16)(hnew - (float)h16);
            if (s < 269) {   // prefetch next step's gi
                const float* gp = gi + ((long)chain * 270 + s + 1) * H3;
                g0 = gp[c];
                g1 = gp[H_ + c];
                g2v = gp[2 * H_ + c];
            }
        }
    }
}

// ---------------------------------------------------------------- attention softmax
__global__ __launch_bounds__(256) void k_attn_softmax(const float* __restrict__ lg,
                                                      const int* __restrict__ x, f16* __restrict__ ah) {
    __shared__ float red[256];
    int r = blockIdx.x, tid = threadIdx.x;
    int b = r / 270;
    const float* lr = lg + (long)r * S_;
    const int* xb = x + (long)b * S_;
    float v0 = lr[tid];
    if (xb[tid] == 0) v0 = -1e9f;
    float v1 = lr[tid + 256];
    if (xb[tid + 256] == 0) v1 = -1e9f;
    red[tid] = fmaxf(v0, v1);
    __syncthreads();
    for (int o = 128; o > 0; o >>= 1) {
        if (tid < o) red[tid] = fmaxf(red[tid], red[tid + o]);
        __syncthreads();
    }
    float m = red[0];
    __syncthreads();
    float e0 = __expf(v0 - m), e1 = __expf(v1 - m);
    red[tid] = e0 + e1;
    __syncthreads();
    for (int o = 128; o > 0; o >>= 1) {
        if (tid < o) red[tid] += red[tid + o];
        __syncthreads();
    }
    float inv = 1.f / red[0];
    ah[(long)r * S_ + tid] = (f16)(e0 * inv);
    ah[(long)r * S_ + tid + 256] = (f16)(e1 * inv);
}

// ---------------------------------------------------------------- p_gen
__global__ __launch_bounds__(256) void k_pgen(const f16* __restrict__ Wall, const f16* __restrict__ Hhi,
                                              const f16* __restrict__ Hlo, const float* __restrict__ ctx,
                                              const float* __restrict__ wg, const float* __restrict__ wgb,
                                              float* __restrict__ pg) {
    __shared__ float red[256];
    int r = blockIdx.x, tid = threadIdx.x;
    float a = 0.f;
    for (int i = tid; i < H_; i += 256) {
        a += (float)Wall[(long)r * H_ + i] * wg[i];
        a += ((float)Hhi[(long)r * H_ + i] + (float)Hlo[(long)r * H_ + i]) * wg[H_ + i];
        a += ctx[(long)r * H_ + i] * wg[2 * H_ + i];
    }
    red[tid] = a;
    __syncthreads();
    for (int o = 128; o > 0; o >>= 1) {
        if (tid < o) red[tid] += red[tid + o];
        __syncthreads();
    }
    if (tid == 0) pg[r] = 1.f / (1.f + expf(-(red[0] + wgb[0])));
}

// ---------------------------------------------------------------- fused rinv + finalize + scatter
// One block per row: rinv from psum; stream exp-row through LDS scaling by
// pg*rinv; pointer-scatter via LDS atomics; write the f32 row back once.
__global__ __launch_bounds__(256, 1) void k_fin3(float* __restrict__ out,
                                                 const float* __restrict__ psum,
                                                 const float* __restrict__ pg,
                                                 const f16* __restrict__ ah,
                                                 const int* __restrict__ x) {
    __shared__ float row[V_];
    __shared__ float red[256];
    const int r = blockIdx.x, tid = threadIdx.x;
    const int b = r / 270;
    float s = 0.f;
    for (int i = tid; i < VNT; i += 256) s += psum[(long)i * R_ + r];
    red[tid] = s;
    __syncthreads();
    for (int o = 128; o > 0; o >>= 1) {
        if (tid < o) red[tid] += red[tid + o];
        __syncthreads();
    }
    const float pgv = pg[r];
    const float scale = pgv / red[0];
    float* orow = out + (long)r * V_;
    for (int i = tid; i < V_ / 4; i += 256) {
        f32x4 v = ((const f32x4*)orow)[i];
        v.x *= scale;
        v.y *= scale;
        v.z *= scale;
        v.w *= scale;
        ((f32x4*)row)[i] = v;
    }
    __syncthreads();
    const float om = 1.f - pgv;
    for (int s2 = tid; s2 < S_; s2 += 256) {
        int xv = x[(long)b * S_ + s2];
        if (xv != 0) {
            float a = (float)ah[(long)r * S_ + s2];
            if (a != 0.f) atomicAdd(&row[xv], om * a);
        }
    }
    __syncthreads();
    for (int i = tid; i < V_ / 4; i += 256)
        ((f32x4*)orow)[i] = ((const f32x4*)row)[i];
}

// ---------------------------------------------------------------- host
extern "C" void kernel_launch(void* const* d_in, const int* in_sizes, int n_in, void* d_out,
                              int out_size, void* d_ws, size_t ws_size, hipStream_t stream) {
    (void)in_sizes; (void)n_in; (void)out_size; (void)ws_size;
    const int* x = (const int*)d_in[0];
    const float* dec = (const float*)d_in[1];
    const float* enc = (const float*)d_in[2];
    const float* hid = (const float*)d_in[3];
    const int* tea = (const int*)d_in[4];
    const float* emb = (const float*)d_in[6];
    const float* wih = (const float*)d_in[7];
    const float* whh = (const float*)d_in[8];
    const float* bih = (const float*)d_in[9];
    const float* bhh = (const float*)d_in[10];
    const float* wgw = (const float*)d_in[11];
    const float* wgb = (const float*)d_in[12];
    float* out = (float*)d_out;

    char* w = (char*)d_ws;
    size_t off = 0;
    auto alloc = [&](size_t bytes) {
        void* p = w + off;
        off = (off + bytes + 255) & ~(size_t)255;
        return p;
    };
    ull* hbuf = (ull*)alloc(8 * 1536 * 8);          // [chain][parity][768] seq-tagged h
    f16* Wall = (f16*)alloc((size_t)R_ * H_ * 2);
    f16* wih16 = (f16*)alloc((size_t)H3 * H_ * 2);
    float* giA = (float*)alloc((size_t)R_ * H3 * 4);
    f16* Hhi = (f16*)alloc((size_t)R_ * H_ * 2);
    f16* Hlo = (f16*)alloc((size_t)R_ * H_ * 2);
    f16* emb16 = (f16*)alloc((size_t)V_ * H_ * 2);
    f16* ehi = (f16*)alloc((size_t)B_ * S_ * H_ * 2);
    f16* elo = (f16*)alloc((size_t)B_ * S_ * H_ * 2);
    f16* encT = (f16*)alloc((size_t)B_ * H_ * S_ * 2);
    float* lgH = (float*)alloc((size_t)R_ * S_ * 4);
    f16* ah = (f16*)alloc((size_t)R_ * S_ * 2);
    float* ctx = (float*)alloc((size_t)R_ * H_ * 4);
    float* pg = (float*)alloc(R_ * 4);
    float* psum = (float*)alloc((size_t)VNT * R_ * 4);

    const int nH = 8 * 1536 * 2;                    // hbuf as ints
    k_zero<<<(nH + 255) / 256, 256, 0, stream>>>((int*)hbuf, nH);
    k_cast<<<512, 256, 0, stream>>>(wih, wih16, (long)H3 * H_);
    k_build_wall<<<R_, 256, 0, stream>>>(emb, dec, tea, Wall);
    k_init_h<<<24, 256, 0, stream>>>(hid, hbuf);

    // gi = W_all @ w_ih^T + b_ih
    {
        dim3 g(H3 / 128, (R_ + 127) / 128, 1);
        k_gemm<1><<<g, 256, 0, stream>>>(Wall, wih16, giA, bih, R_, H3, H_, 0, 0, 0);
    }
    // recurrence (blocks 0-191) + hidden preps on idle CUs (blocks 192-255)
    k_gru<<<256, 256, 0, stream>>>(giA, whh, bhh, hbuf, Hhi, Hlo,
                                   emb, emb16, enc, ehi, elo, encT);

    // attention logits (merged hi/lo): Hhi*Ehi + Hhi*Elo + Hlo*Ehi
    {
        dim3 g(S_ / 128, 3, 8);
        k_attn3<<<g, 256, 0, stream>>>(Hhi, Hlo, ehi, elo, lgH, 270, S_, H_,
                                       270L * H_, (long)S_ * H_, 270L * S_);
    }
    k_attn_softmax<<<R_, 256, 0, stream>>>(lgH, x, ah);
    {
        dim3 g(H_ / 128, 3, 8);
        k_gemm<0><<<g, 256, 0, stream>>>(ah, encT, ctx, nullptr, 270, H_, S_, 270L * S_, (long)H_ * S_, 270L * H_);
    }
    k_pgen<<<R_, 256, 0, stream>>>(Wall, Hhi, Hlo, ctx, wgw, wgb, pg);

    // vocab: out = exp(Hhi @ emb16^T), row partial sums -> psum (XCD-swizzled grid)
    k_vocab<<<VMT * VNT, 256, 0, stream>>>(Hhi, emb16, out, psum);
    // fused rinv + finalize + pointer-scatter
    k_fin3<<<R_, 256, 0, stream>>>(out, psum, pg, ah, x);
}